// Round 7
// baseline (223.640 us; speedup 1.0000x reference)
//
#include <hip/hip_runtime.h>
#include <stdint.h>

#define H 768
#define NHEAD 12
#define HDIM 64
#define BATCH 16
#define TSEQ 512
#define BT (BATCH*TSEQ)      // 8192 tokens
#define C3 (3*H)             // 2304
#define LDQK 1536            // packed Q,K row stride

typedef __attribute__((ext_vector_type(8))) short short8;
typedef __attribute__((ext_vector_type(4))) float floatx4;
typedef unsigned short u16;

__device__ __forceinline__ u16 f2bf(float f) {
    union { float f; unsigned int u; } v; v.f = f;
    unsigned int u = v.u;
    return (u16)((u + 0x7FFFu + ((u >> 16) & 1u)) >> 16);
}

// async global->LDS, 16B per lane; LDS dest = wave-uniform base + lane*16
__device__ __forceinline__ void async_ld16(const void* g, void* l) {
    __builtin_amdgcn_global_load_lds((__attribute__((address_space(1))) void*)g,
                                     (__attribute__((address_space(3))) void*)l,
                                     16, 0, 0);
}

// ---------------------------------------------------------------------------
// Prep (merged): blocks [0,9216): Wall/Wobf/bias; blocks [9216,15360): x->bf16
// ---------------------------------------------------------------------------
#define PREP_BLOCKS 9216     // 4*H*H/256
#define CVT_BLOCKS  6144     // BT*H/1024
__global__ void prep_kernel(const float* __restrict__ Wq, const float* __restrict__ bq,
                            const float* __restrict__ Aq, const float* __restrict__ Bq,
                            const float* __restrict__ Wk, const float* __restrict__ bk,
                            const float* __restrict__ Wv, const float* __restrict__ bv,
                            const float* __restrict__ Av, const float* __restrict__ Bv,
                            const float* __restrict__ Wo, const float* __restrict__ x,
                            u16* __restrict__ Wall, u16* __restrict__ Wobf,
                            float* __restrict__ bias_all, u16* __restrict__ xb)
{
    const int bid = blockIdx.x;
    if (bid >= PREP_BLOCKS) {
        const int i = ((bid - PREP_BLOCKS) * 256 + threadIdx.x) * 4;
        const float4 v = *(const float4*)(x + i);
        u16 o[4] = { f2bf(v.x), f2bf(v.y), f2bf(v.z), f2bf(v.w) };
        *(uint2*)(xb + i) = *(const uint2*)o;
        return;
    }
    const int idx = bid * 256 + threadIdx.x;   // < 4*H*H
    const int r = idx / H;
    const int c = idx - r * H;
    if (r < H) {
        float v = Wq[idx] + 2.0f * (Bq[r*4+0]*Aq[c] + Bq[r*4+1]*Aq[H+c] +
                                    Bq[r*4+2]*Aq[2*H+c] + Bq[r*4+3]*Aq[3*H+c]);
        Wall[idx] = f2bf(v);
    } else if (r < 2*H) {
        Wall[idx] = f2bf(Wk[idx - H*H]);
    } else if (r < 3*H) {
        const int rr = r - 2*H;
        float v = Wv[rr*H + c] + 2.0f * (Bv[rr*4+0]*Av[c] + Bv[rr*4+1]*Av[H+c] +
                                         Bv[rr*4+2]*Av[2*H+c] + Bv[rr*4+3]*Av[3*H+c]);
        Wall[idx] = f2bf(v);
    } else {
        Wobf[idx - 3*H*H] = f2bf(Wo[idx - 3*H*H]);
    }
    if (idx < C3) {
        bias_all[idx] = (idx < H) ? bq[idx] : (idx < 2*H ? bk[idx - H] : bv[idx - 2*H]);
    }
}

// ---------------------------------------------------------------------------
// GEMM: C[M][N] = A[M][K] * B[N][K]^T + bias[N]   (A,B bf16, acc fp32)
// Exact r3 structure (best measured across 6 rounds of A/B: 55.6 us):
// 2-barrier K-loop, BK=32, LINEAR coalesced global_load_lds staging, 16 KB
// LDS (single-buffered; dbuf/BK64/swizzle all regressed). 8-way LDS read
// conflicts accepted (~10% tax; fixing them broke DMA coalescing: r5).
// TM = M-tile (128 or 64). MODE 0: fp32 out. MODE 1: QKV with V transposed
// into vt[bh][d][t].
// ---------------------------------------------------------------------------
template<int MODE, int TM>
__global__ __launch_bounds__(256)
void gemm_bt(const u16* __restrict__ A, const u16* __restrict__ Bw,
             const float* __restrict__ bias, void* __restrict__ Cout,
             u16* __restrict__ Vout, int K, int ldc)
{
    constexpr int MT = TM / 32;            // m-tiles per wave (4 or 2)
    __shared__ u16 Ablk[TM * 32];
    __shared__ u16 Bblk[128 * 32];
    const int tid  = threadIdx.x;
    const int wave = tid >> 6;
    const int lane = tid & 63;
    const int quad = lane >> 4;
    const int l16  = lane & 15;
    const int m0 = blockIdx.y * TM;
    const int n0 = blockIdx.x * 128;
    const int mw = (wave & 1) * (TM / 2);
    const int nw = (wave >> 1) * 64;

    // staging (linear): lane i -> row i>>2, k-chunk i&3 (16B); wave covers
    // A rows [wave*(TM/4), +TM/4) and B rows [wave*32, +32)
    const int srow = lane >> 2;
    const int scol = (lane & 3) * 8;
    const int arow0 = wave * (TM / 4);
    const u16* gA = A  + (size_t)(m0 + arow0 + srow) * K + scol;
    const u16* gB = Bw + (size_t)(n0 + wave*32 + srow) * K + scol;
    u16* lA = Ablk + arow0 * 32;
    u16* lB = Bblk + wave * 32 * 32;

    floatx4 acc[MT][4] = {};

    for (int k0 = 0; k0 < K; k0 += 32) {
        __syncthreads();
        async_ld16(gA + k0, lA);
        if (TM == 128) async_ld16(gA + k0 + 16*K, lA + 16*32);
        async_ld16(gB + k0, lB);
        async_ld16(gB + k0 + 16*K, lB + 16*32);
        __syncthreads();
        short8 af[MT], bfr[4];
        #pragma unroll
        for (int mt = 0; mt < MT; mt++)
            af[mt] = *(const short8*)(Ablk + (mw + mt*16 + l16)*32 + quad*8);
        #pragma unroll
        for (int nt = 0; nt < 4; nt++)
            bfr[nt] = *(const short8*)(Bblk + (nw + nt*16 + l16)*32 + quad*8);
        #pragma unroll
        for (int mt = 0; mt < MT; mt++)
            #pragma unroll
            for (int nt = 0; nt < 4; nt++)
                acc[mt][nt] = __builtin_amdgcn_mfma_f32_16x16x32_bf16(af[mt], bfr[nt], acc[mt][nt], 0, 0, 0);
    }

    // epilogue: C layout col=lane&15, row=quad*4+reg
    if (MODE == 1 && n0 >= LDQK) {
        const int nv = n0 + nw - LDQK;
        const int b  = m0 >> 9;
        #pragma unroll
        for (int nt = 0; nt < 4; nt++) {
            const int n  = nv + nt*16 + l16;        // 0..767
            const int hh = n >> 6, d = n & 63;
            const float bv = bias[LDQK + n];
            u16* vp = Vout + ((size_t)(b*NHEAD + hh) * HDIM + d) * TSEQ;
            #pragma unroll
            for (int mt = 0; mt < MT; mt++) {
                const int t0 = (m0 & 511) + mw + mt*16 + quad*4;
                u16 pack[4];
                #pragma unroll
                for (int r = 0; r < 4; r++) pack[r] = f2bf(acc[mt][nt][r] + bv);
                *(uint2*)(vp + t0) = *(const uint2*)pack;
            }
        }
    } else {
        #pragma unroll
        for (int nt = 0; nt < 4; nt++) {
            const int n = n0 + nw + nt*16 + l16;
            const float bv = bias[n];
            #pragma unroll
            for (int mt = 0; mt < MT; mt++) {
                #pragma unroll
                for (int r = 0; r < 4; r++) {
                    const int m = m0 + mw + mt*16 + quad*4 + r;
                    const float v = acc[mt][nt][r] + bv;
                    if (MODE == 1) ((u16*)Cout)[(size_t)m * ldc + n] = f2bf(v);
                    else           ((float*)Cout)[(size_t)m * ldc + n] = v;
                }
            }
        }
    }
}

// ---------------------------------------------------------------------------
// Attention: block-shared double-buffered LDS K/V staging, 1 barrier/iter,
// XOR-swizzled LDS (required here: unswizzled K-frag reads would be 16-way
// conflicted; r6 counters confirm ~0 attn conflicts). ~25 us estimated.
// Block = (b,h, 128 q rows); wave owns 32 q rows (2 m-tiles).
// ---------------------------------------------------------------------------
#define PSTRIDE 40   // u16; 80 B rows: conflict-free writes + b128 reads

__global__ __launch_bounds__(256)
void attn_kernel(const u16* __restrict__ qk, const u16* __restrict__ vt,
                 const int* __restrict__ mask, u16* __restrict__ attn_out)
{
    __shared__ float maskadd[TSEQ];                 // 2 KB
    __shared__ u16 Kbuf[2][32 * 64];                // 8 KB  [key][d], swizzled
    __shared__ u16 Vbuf[2][64 * 32];                // 8 KB  [d][key], swizzled
    __shared__ u16 Pbuf[4][2][16 * PSTRIDE];        // 10 KB

    const int qt = blockIdx.x;        // 0..3 (128 q rows per block)
    const int bh = blockIdx.y;        // 0..191
    const int b = bh / NHEAD, h = bh - b * NHEAD;
    const int tid  = threadIdx.x;
    const int wave = tid >> 6;
    const int lane = tid & 63;
    const int quad = lane >> 4;
    const int l16  = lane & 15;

    for (int i = tid; i < TSEQ; i += 256)
        maskadd[i] = (mask[b*TSEQ + i] == 0) ? -1e9f : 0.0f;

    const size_t btok = (size_t)b * TSEQ;
    const int q0 = qt * 128 + wave * 32;

    // Q fragments for 2 row-tiles: A[m=l16][k=quad*8+j], two d-halves
    short8 qf[2][2];
    #pragma unroll
    for (int m = 0; m < 2; m++) {
        const u16* qp = qk + (btok + q0 + m*16 + l16) * LDQK + h*HDIM + quad*8;
        qf[m][0] = *(const short8*)qp;
        qf[m][1] = *(const short8*)(qp + 32);
    }

    const u16* kglob = qk + btok * LDQK + H + h*HDIM;   // K rows, stride LDQK
    const u16* vglob = vt + (size_t)bh * HDIM * TSEQ;   // V^T rows, stride TSEQ

    auto stage = [&](int kb, int pp) {
        {   // K[key][d]: lane i -> key kb+w*8+(i>>3), phys chunk i&7 = logical ^ (key&7)
            const int r = lane >> 3;
            const int g = (lane & 7) ^ r;
            async_ld16(kglob + (size_t)(kb + wave*8 + r) * LDQK + g*8,
                       &Kbuf[pp][wave*8*64]);
        }
        {   // V^T[d][key]: lane i -> d w*16+(i>>2), phys chunk i&3 = logical ^ ((d>>1)&3)
            const int dr = lane >> 2;
            const int g  = (lane & 3) ^ ((dr >> 1) & 3);
            async_ld16(vglob + (size_t)(wave*16 + dr) * TSEQ + kb + g*8,
                       &Vbuf[pp][wave*16*32]);
        }
    };

    floatx4 o[2][4] = {};              // 2 x (16q x 64d), C-layout
    float lsum[2][4] = {};

    auto compute = [&](int kb, int pp) {
        const u16* Kb_ = Kbuf[pp];
        const u16* Vb_ = Vbuf[pp];
        short8 kf[2][2];
        #pragma unroll
        for (int t = 0; t < 2; t++)
            #pragma unroll
            for (int h2 = 0; h2 < 2; h2++)
                kf[t][h2] = *(const short8*)(Kb_ + (t*16 + l16)*64 + (((h2*4 + quad) ^ (l16 & 7))*8));
        short8 vf[4];
        #pragma unroll
        for (int dt = 0; dt < 4; dt++)
            vf[dt] = *(const short8*)(Vb_ + (dt*16 + l16)*32 + ((quad ^ ((l16 >> 1) & 3))*8));

        floatx4 s[2][2];
        #pragma unroll
        for (int m = 0; m < 2; m++)
            #pragma unroll
            for (int t = 0; t < 2; t++) {
                floatx4 acc = {0.f, 0.f, 0.f, 0.f};
                acc = __builtin_amdgcn_mfma_f32_16x16x32_bf16(qf[m][0], kf[t][0], acc, 0, 0, 0);
                acc = __builtin_amdgcn_mfma_f32_16x16x32_bf16(qf[m][1], kf[t][1], acc, 0, 0, 0);
                s[m][t] = acc;
            }
        const float m0 = maskadd[kb + l16];
        const float m1 = maskadd[kb + 16 + l16];
        #pragma unroll
        for (int m = 0; m < 2; m++) {
            u16* Pw = Pbuf[wave][m];
            #pragma unroll
            for (int r = 0; r < 4; r++) {
                const float p0 = __expf(s[m][0][r] * 0.125f + m0);
                const float p1 = __expf(s[m][1][r] * 0.125f + m1);
                lsum[m][r] += p0 + p1;
                Pw[(quad*4 + r) * PSTRIDE + l16]      = f2bf(p0);
                Pw[(quad*4 + r) * PSTRIDE + 16 + l16] = f2bf(p1);
            }
        }
        #pragma unroll
        for (int m = 0; m < 2; m++) {
            const short8 pa = *(const short8*)(Pbuf[wave][m] + l16 * PSTRIDE + quad*8);
            #pragma unroll
            for (int dt = 0; dt < 4; dt++)
                o[m][dt] = __builtin_amdgcn_mfma_f32_16x16x32_bf16(pa, vf[dt], o[m][dt], 0, 0, 0);
        }
    };

    stage(0, 0);
    for (int it = 0; it < 16; it++) {
        __syncthreads();
        if (it < 15) stage((it + 1) * 32, (it + 1) & 1);
        compute(it * 32, it & 1);
    }

    #pragma unroll
    for (int m = 0; m < 2; m++) {
        float inv[4];
        #pragma unroll
        for (int r = 0; r < 4; r++) {
            float l = lsum[m][r];
            l += __shfl_xor(l, 1);
            l += __shfl_xor(l, 2);
            l += __shfl_xor(l, 4);
            l += __shfl_xor(l, 8);
            inv[r] = 1.0f / l;
        }
        #pragma unroll
        for (int dt = 0; dt < 4; dt++)
            #pragma unroll
            for (int r = 0; r < 4; r++) {
                const int q = q0 + m*16 + quad*4 + r;
                attn_out[(btok + q) * H + h*HDIM + dt*16 + l16] = f2bf(o[m][dt][r] * inv[r]);
            }
    }
}

// ---------------------------------------------------------------------------
extern "C" void kernel_launch(void* const* d_in, const int* in_sizes, int n_in,
                              void* d_out, int out_size, void* d_ws, size_t ws_size,
                              hipStream_t stream)
{
    const float* x   = (const float*)d_in[0];
    const int* mask  = (const int*)d_in[1];
    const float* Wq  = (const float*)d_in[2];
    const float* bq  = (const float*)d_in[3];
    const float* Aq  = (const float*)d_in[4];
    const float* Bq  = (const float*)d_in[5];
    const float* Wk  = (const float*)d_in[6];
    const float* bk  = (const float*)d_in[7];
    const float* Wv  = (const float*)d_in[8];
    const float* bv  = (const float*)d_in[9];
    const float* Av  = (const float*)d_in[10];
    const float* Bv  = (const float*)d_in[11];
    const float* Wo  = (const float*)d_in[12];
    const float* bo  = (const float*)d_in[13];

    char* ws = (char*)d_ws;
    u16*   xb      = (u16*)  (ws);                 // 12,582,912 B
    u16*   Wall    = (u16*)  (ws + 12582912);      //  3,538,944 B
    u16*   Wobf    = (u16*)  (ws + 16121856);      //  1,179,648 B
    float* biasall = (float*)(ws + 17301504);      //      9,216 B
    u16*   qk      = (u16*)  (ws + 17310720);      // 25,165,824 B
    u16*   vt      = (u16*)  (ws + 42476544);      // 12,582,912 B
    u16*   attn_o  = (u16*)  (ws + 55059456);      // 12,582,912 B (end 67,642,368)

    prep_kernel<<<PREP_BLOCKS + CVT_BLOCKS, 256, 0, stream>>>(
        Wq, bq, Aq, Bq, Wk, bk, Wv, bv, Av, Bv, Wo, x, Wall, Wobf, biasall, xb);
    gemm_bt<1,128><<<dim3(C3/128, BT/128), 256, 0, stream>>>(xb, Wall, biasall, qk, vt, H, LDQK);
    attn_kernel<<<dim3(TSEQ/128, BATCH*NHEAD), 256, 0, stream>>>(qk, vt, mask, attn_o);
    gemm_bt<0,64><<<dim3(H/128, BT/64), 256, 0, stream>>>(attn_o, Wobf, bo, d_out, nullptr, H, H);
}

// Round 8
// 214.112 us; speedup vs baseline: 1.0445x; 1.0445x over previous
//
#include <hip/hip_runtime.h>
#include <stdint.h>

#define H 768
#define NHEAD 12
#define HDIM 64
#define BATCH 16
#define TSEQ 512
#define BT (BATCH*TSEQ)      // 8192 tokens
#define C3 (3*H)             // 2304

typedef __attribute__((ext_vector_type(8))) short short8;
typedef __attribute__((ext_vector_type(4))) float floatx4;
typedef unsigned short u16;

__device__ __forceinline__ u16 f2bf(float f) {
    union { float f; unsigned int u; } v; v.f = f;
    unsigned int u = v.u;
    return (u16)((u + 0x7FFFu + ((u >> 16) & 1u)) >> 16);
}

// async global->LDS, 16B per lane; LDS dest = wave-uniform base + lane*16
__device__ __forceinline__ void async_ld16(const void* g, void* l) {
    __builtin_amdgcn_global_load_lds((__attribute__((address_space(1))) void*)g,
                                     (__attribute__((address_space(3))) void*)l,
                                     16, 0, 0);
}

// ---------------------------------------------------------------------------
// Prep (merged): blocks [0,9216): Wall/Wobf/bias; blocks [9216,15360): x->bf16
// ---------------------------------------------------------------------------
#define PREP_BLOCKS 9216     // 4*H*H/256
#define CVT_BLOCKS  6144     // BT*H/1024
__global__ void prep_kernel(const float* __restrict__ Wq, const float* __restrict__ bq,
                            const float* __restrict__ Aq, const float* __restrict__ Bq,
                            const float* __restrict__ Wk, const float* __restrict__ bk,
                            const float* __restrict__ Wv, const float* __restrict__ bv,
                            const float* __restrict__ Av, const float* __restrict__ Bv,
                            const float* __restrict__ Wo, const float* __restrict__ x,
                            u16* __restrict__ Wall, u16* __restrict__ Wobf,
                            float* __restrict__ bias_all, u16* __restrict__ xb)
{
    const int bid = blockIdx.x;
    if (bid >= PREP_BLOCKS) {
        const int i = ((bid - PREP_BLOCKS) * 256 + threadIdx.x) * 4;
        const float4 v = *(const float4*)(x + i);
        u16 o[4] = { f2bf(v.x), f2bf(v.y), f2bf(v.z), f2bf(v.w) };
        *(uint2*)(xb + i) = *(const uint2*)o;
        return;
    }
    const int idx = bid * 256 + threadIdx.x;   // < 4*H*H
    const int r = idx / H;
    const int c = idx - r * H;
    if (r < H) {
        float v = Wq[idx] + 2.0f * (Bq[r*4+0]*Aq[c] + Bq[r*4+1]*Aq[H+c] +
                                    Bq[r*4+2]*Aq[2*H+c] + Bq[r*4+3]*Aq[3*H+c]);
        Wall[idx] = f2bf(v);
    } else if (r < 2*H) {
        Wall[idx] = f2bf(Wk[idx - H*H]);
    } else if (r < 3*H) {
        const int rr = r - 2*H;
        float v = Wv[rr*H + c] + 2.0f * (Bv[rr*4+0]*Av[c] + Bv[rr*4+1]*Av[H+c] +
                                         Bv[rr*4+2]*Av[2*H+c] + Bv[rr*4+3]*Av[3*H+c]);
        Wall[idx] = f2bf(v);
    } else {
        Wobf[idx - 3*H*H] = f2bf(Wo[idx - 3*H*H]);
    }
    if (idx < C3) {
        bias_all[idx] = (idx < H) ? bq[idx] : (idx < 2*H ? bk[idx - H] : bv[idx - 2*H]);
    }
}

// ---------------------------------------------------------------------------
// GEMM: C[M][N] = A[M][K] * B[N][K]^T + bias[N]   (A,B bf16, acc fp32)
// r4's K-loop (fastest measured loop: BK=64, XOR-swizzled LDS, 0 bank
// conflicts, linear-per-8-lane-row DMA) + r3's PLAIN epilogue (r7 isolated
// the V-transposed epilogue as a ~16us RMW tax -> removed; V^T is done by
// the separate vtrans kernel).  MODE 0: fp32 out. MODE 1: bf16 out.
// ---------------------------------------------------------------------------
template<int MODE, int TM>
__global__ __launch_bounds__(256)
void gemm_bt(const u16* __restrict__ A, const u16* __restrict__ Bw,
             const float* __restrict__ bias, void* __restrict__ Cout,
             int K, int ldc)
{
    constexpr int MT = TM / 32;            // m-tiles per wave (4 or 2)
    __shared__ u16 Ablk[TM * 64];
    __shared__ u16 Bblk[128 * 64];
    const int tid  = threadIdx.x;
    const int wave = tid >> 6;
    const int lane = tid & 63;
    const int quad = lane >> 4;
    const int l16  = lane & 15;
    const int m0 = blockIdx.y * TM;
    const int n0 = blockIdx.x * 128;
    const int mw = (wave & 1) * (TM / 2);
    const int nw = (wave >> 1) * 64;

    // staging: wave covers A rows [wave*(TM/4), +TM/4), B rows [wave*32,+32);
    // each async op = 8 rows. lane i -> row r8=i>>3, phys chunk i&7 holds
    // logical chunk (i&7)^r8 (XOR swizzle; r4-verified conflict-free & fast)
    const int r8 = lane >> 3;
    const int kgs = ((lane & 7) ^ r8) * 8;
    const u16* gA = A  + (size_t)(m0 + wave*(TM/4) + r8) * K + kgs;
    const u16* gB = Bw + (size_t)(n0 + wave*32      + r8) * K + kgs;
    u16* lA = Ablk + wave * (TM/4) * 64;
    u16* lB = Bblk + wave * 32 * 64;

    floatx4 acc[MT][4] = {};
    const int sw = l16 & 7;    // reader swizzle key (row&7 == l16&7)

    for (int k0 = 0; k0 < K; k0 += 64) {
        __syncthreads();
        #pragma unroll
        for (int j = 0; j < TM/32; j++)
            async_ld16(gA + k0 + (size_t)(j*8) * K, lA + j*8*64);
        #pragma unroll
        for (int j = 0; j < 4; j++)
            async_ld16(gB + k0 + (size_t)(j*8) * K, lB + j*8*64);
        __syncthreads();
        #pragma unroll
        for (int kk = 0; kk < 2; kk++) {
            short8 af[MT], bfr[4];
            #pragma unroll
            for (int mt = 0; mt < MT; mt++)
                af[mt] = *(const short8*)(Ablk + (mw + mt*16 + l16)*64 + ((quad + 4*kk) ^ sw)*8);
            #pragma unroll
            for (int nt = 0; nt < 4; nt++)
                bfr[nt] = *(const short8*)(Bblk + (nw + nt*16 + l16)*64 + ((quad + 4*kk) ^ sw)*8);
            #pragma unroll
            for (int mt = 0; mt < MT; mt++)
                #pragma unroll
                for (int nt = 0; nt < 4; nt++)
                    acc[mt][nt] = __builtin_amdgcn_mfma_f32_16x16x32_bf16(af[mt], bfr[nt], acc[mt][nt], 0, 0, 0);
        }
    }

    // plain epilogue (r3-proven): C layout col=lane&15, row=quad*4+reg
    #pragma unroll
    for (int nt = 0; nt < 4; nt++) {
        const int n = n0 + nw + nt*16 + l16;
        const float bv = bias[n];
        #pragma unroll
        for (int mt = 0; mt < MT; mt++) {
            #pragma unroll
            for (int r = 0; r < 4; r++) {
                const int m = m0 + mw + mt*16 + quad*4 + r;
                const float v = acc[mt][nt][r] + bv;
                if (MODE == 1) ((u16*)Cout)[(size_t)m * ldc + n] = f2bf(v);
                else           ((float*)Cout)[(size_t)m * ldc + n] = v;
            }
        }
    }
}

// ---------------------------------------------------------------------------
// V transpose: vt[bh][d][t] <- qkv[b*512+t][2H + h*64 + d]   (bf16)
// r3-proven kernel (~8us): full-line reads and writes both sides.
// ---------------------------------------------------------------------------
#define TSTRIDE 72   // u16; 144 B rows (16B-aligned, conflict-free writes)
__global__ __launch_bounds__(256)
void vtrans_kernel(const u16* __restrict__ qkv, u16* __restrict__ vt)
{
    __shared__ u16 Lt[64 * TSTRIDE];
    const int tc = blockIdx.x;        // token chunk of 64
    const int bh = blockIdx.y;
    const int b = bh / NHEAD, h = bh - b * NHEAD;
    const int tid = threadIdx.x;

    {
        const int tok = tid & 63;
        const int dg  = (tid >> 6) * 16;
        const u16* p = qkv + (size_t)(b*TSEQ + tc*64 + tok) * C3 + 2*H + h*HDIM + dg;
        u16 tmp[16];
        *(short8*)tmp       = *(const short8*)p;
        *(short8*)(tmp + 8) = *(const short8*)(p + 8);
        #pragma unroll
        for (int j = 0; j < 16; j++) Lt[(dg + j) * TSTRIDE + tok] = tmp[j];
    }
    __syncthreads();
    {
        const int d  = tid >> 2;
        const int ts = (tid & 3) * 16;
        uint4 a0 = *(const uint4*)(Lt + d * TSTRIDE + ts);
        uint4 a1 = *(const uint4*)(Lt + d * TSTRIDE + ts + 8);
        u16* op = vt + ((size_t)bh * HDIM + d) * TSEQ + tc*64 + ts;
        *(uint4*)op       = a0;
        *(uint4*)(op + 8) = a1;
    }
}

// ---------------------------------------------------------------------------
// Attention: block-shared double-buffered LDS K/V staging, 1 barrier/iter,
// XOR-swizzled LDS (attn conflicts ~0 per r6/r7 counters). Q,K from
// qkv[8192][2304]; V^T from vt. Block = (b,h,128 q); wave owns 32 q rows.
// ---------------------------------------------------------------------------
#define PSTRIDE 40   // u16; 80 B rows: conflict-free writes + b128 reads

__global__ __launch_bounds__(256)
void attn_kernel(const u16* __restrict__ qkv, const u16* __restrict__ vt,
                 const int* __restrict__ mask, u16* __restrict__ attn_out)
{
    __shared__ float maskadd[TSEQ];                 // 2 KB
    __shared__ u16 Kbuf[2][32 * 64];                // 8 KB  [key][d], swizzled
    __shared__ u16 Vbuf[2][64 * 32];                // 8 KB  [d][key], swizzled
    __shared__ u16 Pbuf[4][2][16 * PSTRIDE];        // 10 KB

    const int qt = blockIdx.x;        // 0..3 (128 q rows per block)
    const int bh = blockIdx.y;        // 0..191
    const int b = bh / NHEAD, h = bh - b * NHEAD;
    const int tid  = threadIdx.x;
    const int wave = tid >> 6;
    const int lane = tid & 63;
    const int quad = lane >> 4;
    const int l16  = lane & 15;

    for (int i = tid; i < TSEQ; i += 256)
        maskadd[i] = (mask[b*TSEQ + i] == 0) ? -1e9f : 0.0f;

    const size_t btok = (size_t)b * TSEQ;
    const int q0 = qt * 128 + wave * 32;

    // Q fragments for 2 row-tiles: A[m=l16][k=quad*8+j], two d-halves
    short8 qf[2][2];
    #pragma unroll
    for (int m = 0; m < 2; m++) {
        const u16* qp = qkv + (btok + q0 + m*16 + l16) * C3 + h*HDIM + quad*8;
        qf[m][0] = *(const short8*)qp;
        qf[m][1] = *(const short8*)(qp + 32);
    }

    const u16* kglob = qkv + btok * C3 + H + h*HDIM;    // K rows, stride C3
    const u16* vglob = vt + (size_t)bh * HDIM * TSEQ;   // V^T rows, stride TSEQ

    auto stage = [&](int kb, int pp) {
        {   // K[key][d]: lane i -> key kb+w*8+(i>>3), phys chunk i&7 = logical ^ (key&7)
            const int r = lane >> 3;
            const int g = (lane & 7) ^ r;
            async_ld16(kglob + (size_t)(kb + wave*8 + r) * C3 + g*8,
                       &Kbuf[pp][wave*8*64]);
        }
        {   // V^T[d][key]: lane i -> d w*16+(i>>2), phys chunk i&3 = logical ^ ((d>>1)&3)
            const int dr = lane >> 2;
            const int g  = (lane & 3) ^ ((dr >> 1) & 3);
            async_ld16(vglob + (size_t)(wave*16 + dr) * TSEQ + kb + g*8,
                       &Vbuf[pp][wave*16*32]);
        }
    };

    floatx4 o[2][4] = {};              // 2 x (16q x 64d), C-layout
    float lsum[2][4] = {};

    auto compute = [&](int kb, int pp) {
        const u16* Kb_ = Kbuf[pp];
        const u16* Vb_ = Vbuf[pp];
        short8 kf[2][2];
        #pragma unroll
        for (int t = 0; t < 2; t++)
            #pragma unroll
            for (int h2 = 0; h2 < 2; h2++)
                kf[t][h2] = *(const short8*)(Kb_ + (t*16 + l16)*64 + (((h2*4 + quad) ^ (l16 & 7))*8));
        short8 vf[4];
        #pragma unroll
        for (int dt = 0; dt < 4; dt++)
            vf[dt] = *(const short8*)(Vb_ + (dt*16 + l16)*32 + ((quad ^ ((l16 >> 1) & 3))*8));

        floatx4 s[2][2];
        #pragma unroll
        for (int m = 0; m < 2; m++)
            #pragma unroll
            for (int t = 0; t < 2; t++) {
                floatx4 acc = {0.f, 0.f, 0.f, 0.f};
                acc = __builtin_amdgcn_mfma_f32_16x16x32_bf16(qf[m][0], kf[t][0], acc, 0, 0, 0);
                acc = __builtin_amdgcn_mfma_f32_16x16x32_bf16(qf[m][1], kf[t][1], acc, 0, 0, 0);
                s[m][t] = acc;
            }
        const float m0 = maskadd[kb + l16];
        const float m1 = maskadd[kb + 16 + l16];
        #pragma unroll
        for (int m = 0; m < 2; m++) {
            u16* Pw = Pbuf[wave][m];
            #pragma unroll
            for (int r = 0; r < 4; r++) {
                const float p0 = __expf(s[m][0][r] * 0.125f + m0);
                const float p1 = __expf(s[m][1][r] * 0.125f + m1);
                lsum[m][r] += p0 + p1;
                Pw[(quad*4 + r) * PSTRIDE + l16]      = f2bf(p0);
                Pw[(quad*4 + r) * PSTRIDE + 16 + l16] = f2bf(p1);
            }
        }
        #pragma unroll
        for (int m = 0; m < 2; m++) {
            const short8 pa = *(const short8*)(Pbuf[wave][m] + l16 * PSTRIDE + quad*8);
            #pragma unroll
            for (int dt = 0; dt < 4; dt++)
                o[m][dt] = __builtin_amdgcn_mfma_f32_16x16x32_bf16(pa, vf[dt], o[m][dt], 0, 0, 0);
        }
    };

    stage(0, 0);
    for (int it = 0; it < 16; it++) {
        __syncthreads();
        if (it < 15) stage((it + 1) * 32, (it + 1) & 1);
        compute(it * 32, it & 1);
    }

    #pragma unroll
    for (int m = 0; m < 2; m++) {
        float inv[4];
        #pragma unroll
        for (int r = 0; r < 4; r++) {
            float l = lsum[m][r];
            l += __shfl_xor(l, 1);
            l += __shfl_xor(l, 2);
            l += __shfl_xor(l, 4);
            l += __shfl_xor(l, 8);
            inv[r] = 1.0f / l;
        }
        #pragma unroll
        for (int dt = 0; dt < 4; dt++)
            #pragma unroll
            for (int r = 0; r < 4; r++) {
                const int q = q0 + m*16 + quad*4 + r;
                attn_out[(btok + q) * H + h*HDIM + dt*16 + l16] = f2bf(o[m][dt][r] * inv[r]);
            }
    }
}

// ---------------------------------------------------------------------------
extern "C" void kernel_launch(void* const* d_in, const int* in_sizes, int n_in,
                              void* d_out, int out_size, void* d_ws, size_t ws_size,
                              hipStream_t stream)
{
    const float* x   = (const float*)d_in[0];
    const int* mask  = (const int*)d_in[1];
    const float* Wq  = (const float*)d_in[2];
    const float* bq  = (const float*)d_in[3];
    const float* Aq  = (const float*)d_in[4];
    const float* Bq  = (const float*)d_in[5];
    const float* Wk  = (const float*)d_in[6];
    const float* bk  = (const float*)d_in[7];
    const float* Wv  = (const float*)d_in[8];
    const float* bv  = (const float*)d_in[9];
    const float* Av  = (const float*)d_in[10];
    const float* Bv  = (const float*)d_in[11];
    const float* Wo  = (const float*)d_in[12];
    const float* bo  = (const float*)d_in[13];

    char* ws = (char*)d_ws;
    u16*   xb      = (u16*)  (ws);                 // 12,582,912 B (reused as vt)
    u16*   Wall    = (u16*)  (ws + 12582912);      //  3,538,944 B
    u16*   Wobf    = (u16*)  (ws + 16121856);      //  1,179,648 B
    float* biasall = (float*)(ws + 17301504);      //      9,216 B
    u16*   qkv     = (u16*)  (ws + 17310720);      // 37,748,736 B
    u16*   attn_o  = (u16*)  (ws + 55059456);      // 12,582,912 B (end 67,642,368)
    u16*   vt      = xb;     // xb dead after QKV GEMM; reuse for V^T

    prep_kernel<<<PREP_BLOCKS + CVT_BLOCKS, 256, 0, stream>>>(
        Wq, bq, Aq, Bq, Wk, bk, Wv, bv, Av, Bv, Wo, x, Wall, Wobf, biasall, xb);
    gemm_bt<1,128><<<dim3(C3/128, BT/128), 256, 0, stream>>>(xb, Wall, biasall, qkv, H, C3);
    vtrans_kernel<<<dim3(TSEQ/64, BATCH*NHEAD), 256, 0, stream>>>(qkv, vt);
    attn_kernel<<<dim3(TSEQ/128, BATCH*NHEAD), 256, 0, stream>>>(qkv, vt, mask, attn_o);
    gemm_bt<0,64><<<dim3(H/128, BT/64), 256, 0, stream>>>(attn_o, Wobf, bo, d_out, H, H);
}

// Round 9
// 212.916 us; speedup vs baseline: 1.0504x; 1.0056x over previous
//
#include <hip/hip_runtime.h>
#include <stdint.h>

#define H 768
#define NHEAD 12
#define HDIM 64
#define BATCH 16
#define TSEQ 512
#define BT (BATCH*TSEQ)      // 8192 tokens
#define C3 (3*H)             // 2304

typedef __attribute__((ext_vector_type(8))) short short8;
typedef __attribute__((ext_vector_type(4))) float floatx4;
typedef unsigned short u16;

__device__ __forceinline__ u16 f2bf(float f) {
    union { float f; unsigned int u; } v; v.f = f;
    unsigned int u = v.u;
    return (u16)((u + 0x7FFFu + ((u >> 16) & 1u)) >> 16);
}

// async global->LDS, 16B per lane; LDS dest = wave-uniform base + lane*16
__device__ __forceinline__ void async_ld16(const void* g, void* l) {
    __builtin_amdgcn_global_load_lds((__attribute__((address_space(1))) void*)g,
                                     (__attribute__((address_space(3))) void*)l,
                                     16, 0, 0);
}

// ---------------------------------------------------------------------------
// Prep (merged): blocks [0,9216): Wall/Wobf/bias; blocks [9216,15360): x->bf16
// ---------------------------------------------------------------------------
#define PREP_BLOCKS 9216     // 4*H*H/256
#define CVT_BLOCKS  6144     // BT*H/1024
__global__ void prep_kernel(const float* __restrict__ Wq, const float* __restrict__ bq,
                            const float* __restrict__ Aq, const float* __restrict__ Bq,
                            const float* __restrict__ Wk, const float* __restrict__ bk,
                            const float* __restrict__ Wv, const float* __restrict__ bv,
                            const float* __restrict__ Av, const float* __restrict__ Bv,
                            const float* __restrict__ Wo, const float* __restrict__ x,
                            u16* __restrict__ Wall, u16* __restrict__ Wobf,
                            float* __restrict__ bias_all, u16* __restrict__ xb)
{
    const int bid = blockIdx.x;
    if (bid >= PREP_BLOCKS) {
        const int i = ((bid - PREP_BLOCKS) * 256 + threadIdx.x) * 4;
        const float4 v = *(const float4*)(x + i);
        u16 o[4] = { f2bf(v.x), f2bf(v.y), f2bf(v.z), f2bf(v.w) };
        *(uint2*)(xb + i) = *(const uint2*)o;
        return;
    }
    const int idx = bid * 256 + threadIdx.x;   // < 4*H*H
    const int r = idx / H;
    const int c = idx - r * H;
    if (r < H) {
        float v = Wq[idx] + 2.0f * (Bq[r*4+0]*Aq[c] + Bq[r*4+1]*Aq[H+c] +
                                    Bq[r*4+2]*Aq[2*H+c] + Bq[r*4+3]*Aq[3*H+c]);
        Wall[idx] = f2bf(v);
    } else if (r < 2*H) {
        Wall[idx] = f2bf(Wk[idx - H*H]);
    } else if (r < 3*H) {
        const int rr = r - 2*H;
        float v = Wv[rr*H + c] + 2.0f * (Bv[rr*4+0]*Av[c] + Bv[rr*4+1]*Av[H+c] +
                                         Bv[rr*4+2]*Av[2*H+c] + Bv[rr*4+3]*Av[3*H+c]);
        Wall[idx] = f2bf(v);
    } else {
        Wobf[idx - 3*H*H] = f2bf(Wo[idx - 3*H*H]);
    }
    if (idx < C3) {
        bias_all[idx] = (idx < H) ? bq[idx] : (idx < 2*H ? bk[idx - H] : bv[idx - 2*H]);
    }
}

// ---------------------------------------------------------------------------
// GEMM: C[M][N] = A[M][K] * B[N][K]^T + bias[N]   (A,B bf16, acc fp32)
// r4 K-loop (BK=64, XOR-swizzled LDS, 0 conflicts) + plain epilogue (r8:
// 57.7us). NEW: XCD-aware block remap — 1-D grid, xcd=j&7 (dispatch
// round-robin), each XCD owns m-blocks {xcd, xcd+8, ...} iterated n-major,
// so its A-panel stays L2-resident and A is HBM-fetched once chip-wide.
// NN = n-blocks (grid.x = NN * nM). MODE 0: fp32 out. MODE 1: bf16 out.
// ---------------------------------------------------------------------------
template<int MODE, int TM, int NN>
__global__ __launch_bounds__(256)
void gemm_bt(const u16* __restrict__ A, const u16* __restrict__ Bw,
             const float* __restrict__ bias, void* __restrict__ Cout,
             int K, int ldc)
{
    constexpr int MT = TM / 32;            // m-tiles per wave (4 or 2)
    __shared__ u16 Ablk[TM * 64];
    __shared__ u16 Bblk[128 * 64];
    const int tid  = threadIdx.x;
    const int wave = tid >> 6;
    const int lane = tid & 63;
    const int quad = lane >> 4;
    const int l16  = lane & 15;

    // XCD-aware remap: j&7 = XCD (round-robin dispatch); within an XCD,
    // dm cycles fastest over its m-comb, then n advances (n-major).
    const int j   = blockIdx.x;
    const int nM  = gridDim.x / NN;        // 64 (gemm1) / 128 (gemm2)
    const int Mx  = nM >> 3;               // m-blocks per XCD (8 / 16)
    const int xcd = j & 7;
    const int loc = j >> 3;
    const int dm  = loc & (Mx - 1);        // Mx is a power of two
    const int nb  = loc / Mx;
    const int m0 = (xcd + 8*dm) * TM;
    const int n0 = nb * 128;

    const int mw = (wave & 1) * (TM / 2);
    const int nw = (wave >> 1) * 64;

    // staging: wave covers A rows [wave*(TM/4), +TM/4), B rows [wave*32,+32);
    // each async op = 8 rows. lane i -> row r8=i>>3, phys chunk i&7 holds
    // logical chunk (i&7)^r8 (XOR swizzle; conflict-free fragment reads)
    const int r8 = lane >> 3;
    const int kgs = ((lane & 7) ^ r8) * 8;
    const u16* gA = A  + (size_t)(m0 + wave*(TM/4) + r8) * K + kgs;
    const u16* gB = Bw + (size_t)(n0 + wave*32      + r8) * K + kgs;
    u16* lA = Ablk + wave * (TM/4) * 64;
    u16* lB = Bblk + wave * 32 * 64;

    floatx4 acc[MT][4] = {};
    const int sw = l16 & 7;    // reader swizzle key (row&7 == l16&7)

    for (int k0 = 0; k0 < K; k0 += 64) {
        __syncthreads();
        #pragma unroll
        for (int jj = 0; jj < TM/32; jj++)
            async_ld16(gA + k0 + (size_t)(jj*8) * K, lA + jj*8*64);
        #pragma unroll
        for (int jj = 0; jj < 4; jj++)
            async_ld16(gB + k0 + (size_t)(jj*8) * K, lB + jj*8*64);
        __syncthreads();
        #pragma unroll
        for (int kk = 0; kk < 2; kk++) {
            short8 af[MT], bfr[4];
            #pragma unroll
            for (int mt = 0; mt < MT; mt++)
                af[mt] = *(const short8*)(Ablk + (mw + mt*16 + l16)*64 + ((quad + 4*kk) ^ sw)*8);
            #pragma unroll
            for (int nt = 0; nt < 4; nt++)
                bfr[nt] = *(const short8*)(Bblk + (nw + nt*16 + l16)*64 + ((quad + 4*kk) ^ sw)*8);
            #pragma unroll
            for (int mt = 0; mt < MT; mt++)
                #pragma unroll
                for (int nt = 0; nt < 4; nt++)
                    acc[mt][nt] = __builtin_amdgcn_mfma_f32_16x16x32_bf16(af[mt], bfr[nt], acc[mt][nt], 0, 0, 0);
        }
    }

    // plain epilogue: C layout col=lane&15, row=quad*4+reg
    #pragma unroll
    for (int nt = 0; nt < 4; nt++) {
        const int n = n0 + nw + nt*16 + l16;
        const float bv = bias[n];
        #pragma unroll
        for (int mt = 0; mt < MT; mt++) {
            #pragma unroll
            for (int r = 0; r < 4; r++) {
                const int m = m0 + mw + mt*16 + quad*4 + r;
                const float v = acc[mt][nt][r] + bv;
                if (MODE == 1) ((u16*)Cout)[(size_t)m * ldc + n] = f2bf(v);
                else           ((float*)Cout)[(size_t)m * ldc + n] = v;
            }
        }
    }
}

// ---------------------------------------------------------------------------
// V transpose: vt[bh][d][t] <- qkv[b*512+t][2H + h*64 + d]   (bf16)
// ---------------------------------------------------------------------------
#define TSTRIDE 72   // u16; 144 B rows (16B-aligned, conflict-free writes)
__global__ __launch_bounds__(256)
void vtrans_kernel(const u16* __restrict__ qkv, u16* __restrict__ vt)
{
    __shared__ u16 Lt[64 * TSTRIDE];
    const int tc = blockIdx.x;        // token chunk of 64
    const int bh = blockIdx.y;
    const int b = bh / NHEAD, h = bh - b * NHEAD;
    const int tid = threadIdx.x;

    {
        const int tok = tid & 63;
        const int dg  = (tid >> 6) * 16;
        const u16* p = qkv + (size_t)(b*TSEQ + tc*64 + tok) * C3 + 2*H + h*HDIM + dg;
        u16 tmp[16];
        *(short8*)tmp       = *(const short8*)p;
        *(short8*)(tmp + 8) = *(const short8*)(p + 8);
        #pragma unroll
        for (int j = 0; j < 16; j++) Lt[(dg + j) * TSTRIDE + tok] = tmp[j];
    }
    __syncthreads();
    {
        const int d  = tid >> 2;
        const int ts = (tid & 3) * 16;
        uint4 a0 = *(const uint4*)(Lt + d * TSTRIDE + ts);
        uint4 a1 = *(const uint4*)(Lt + d * TSTRIDE + ts + 8);
        u16* op = vt + ((size_t)bh * HDIM + d) * TSEQ + tc*64 + ts;
        *(uint4*)op       = a0;
        *(uint4*)(op + 8) = a1;
    }
}

// ---------------------------------------------------------------------------
// Attention: block-shared double-buffered LDS K/V staging, 1 barrier/iter,
// XOR-swizzled LDS. Q,K from qkv[8192][2304]; V^T from vt.
// Block = (b,h,128 q); wave owns 32 q rows.
// ---------------------------------------------------------------------------
#define PSTRIDE 40   // u16; 80 B rows: conflict-free writes + b128 reads

__global__ __launch_bounds__(256)
void attn_kernel(const u16* __restrict__ qkv, const u16* __restrict__ vt,
                 const int* __restrict__ mask, u16* __restrict__ attn_out)
{
    __shared__ float maskadd[TSEQ];                 // 2 KB
    __shared__ u16 Kbuf[2][32 * 64];                // 8 KB  [key][d], swizzled
    __shared__ u16 Vbuf[2][64 * 32];                // 8 KB  [d][key], swizzled
    __shared__ u16 Pbuf[4][2][16 * PSTRIDE];        // 10 KB

    const int qt = blockIdx.x;        // 0..3 (128 q rows per block)
    const int bh = blockIdx.y;        // 0..191
    const int b = bh / NHEAD, h = bh - b * NHEAD;
    const int tid  = threadIdx.x;
    const int wave = tid >> 6;
    const int lane = tid & 63;
    const int quad = lane >> 4;
    const int l16  = lane & 15;

    for (int i = tid; i < TSEQ; i += 256)
        maskadd[i] = (mask[b*TSEQ + i] == 0) ? -1e9f : 0.0f;

    const size_t btok = (size_t)b * TSEQ;
    const int q0 = qt * 128 + wave * 32;

    // Q fragments for 2 row-tiles: A[m=l16][k=quad*8+j], two d-halves
    short8 qf[2][2];
    #pragma unroll
    for (int m = 0; m < 2; m++) {
        const u16* qp = qkv + (btok + q0 + m*16 + l16) * C3 + h*HDIM + quad*8;
        qf[m][0] = *(const short8*)qp;
        qf[m][1] = *(const short8*)(qp + 32);
    }

    const u16* kglob = qkv + btok * C3 + H + h*HDIM;    // K rows, stride C3
    const u16* vglob = vt + (size_t)bh * HDIM * TSEQ;   // V^T rows, stride TSEQ

    auto stage = [&](int kb, int pp) {
        {   // K[key][d]: lane i -> key kb+w*8+(i>>3), phys chunk i&7 = logical ^ (key&7)
            const int r = lane >> 3;
            const int g = (lane & 7) ^ r;
            async_ld16(kglob + (size_t)(kb + wave*8 + r) * C3 + g*8,
                       &Kbuf[pp][wave*8*64]);
        }
        {   // V^T[d][key]: lane i -> d w*16+(i>>2), phys chunk i&3 = logical ^ ((d>>1)&3)
            const int dr = lane >> 2;
            const int g  = (lane & 3) ^ ((dr >> 1) & 3);
            async_ld16(vglob + (size_t)(wave*16 + dr) * TSEQ + kb + g*8,
                       &Vbuf[pp][wave*16*32]);
        }
    };

    floatx4 o[2][4] = {};              // 2 x (16q x 64d), C-layout
    float lsum[2][4] = {};

    auto compute = [&](int kb, int pp) {
        const u16* Kb_ = Kbuf[pp];
        const u16* Vb_ = Vbuf[pp];
        short8 kf[2][2];
        #pragma unroll
        for (int t = 0; t < 2; t++)
            #pragma unroll
            for (int h2 = 0; h2 < 2; h2++)
                kf[t][h2] = *(const short8*)(Kb_ + (t*16 + l16)*64 + (((h2*4 + quad) ^ (l16 & 7))*8));
        short8 vf[4];
        #pragma unroll
        for (int dt = 0; dt < 4; dt++)
            vf[dt] = *(const short8*)(Vb_ + (dt*16 + l16)*32 + ((quad ^ ((l16 >> 1) & 3))*8));

        floatx4 s[2][2];
        #pragma unroll
        for (int m = 0; m < 2; m++)
            #pragma unroll
            for (int t = 0; t < 2; t++) {
                floatx4 acc = {0.f, 0.f, 0.f, 0.f};
                acc = __builtin_amdgcn_mfma_f32_16x16x32_bf16(qf[m][0], kf[t][0], acc, 0, 0, 0);
                acc = __builtin_amdgcn_mfma_f32_16x16x32_bf16(qf[m][1], kf[t][1], acc, 0, 0, 0);
                s[m][t] = acc;
            }
        const float m0 = maskadd[kb + l16];
        const float m1 = maskadd[kb + 16 + l16];
        #pragma unroll
        for (int m = 0; m < 2; m++) {
            u16* Pw = Pbuf[wave][m];
            #pragma unroll
            for (int r = 0; r < 4; r++) {
                const float p0 = __expf(s[m][0][r] * 0.125f + m0);
                const float p1 = __expf(s[m][1][r] * 0.125f + m1);
                lsum[m][r] += p0 + p1;
                Pw[(quad*4 + r) * PSTRIDE + l16]      = f2bf(p0);
                Pw[(quad*4 + r) * PSTRIDE + 16 + l16] = f2bf(p1);
            }
        }
        #pragma unroll
        for (int m = 0; m < 2; m++) {
            const short8 pa = *(const short8*)(Pbuf[wave][m] + l16 * PSTRIDE + quad*8);
            #pragma unroll
            for (int dt = 0; dt < 4; dt++)
                o[m][dt] = __builtin_amdgcn_mfma_f32_16x16x32_bf16(pa, vf[dt], o[m][dt], 0, 0, 0);
        }
    };

    stage(0, 0);
    for (int it = 0; it < 16; it++) {
        __syncthreads();
        if (it < 15) stage((it + 1) * 32, (it + 1) & 1);
        compute(it * 32, it & 1);
    }

    #pragma unroll
    for (int m = 0; m < 2; m++) {
        float inv[4];
        #pragma unroll
        for (int r = 0; r < 4; r++) {
            float l = lsum[m][r];
            l += __shfl_xor(l, 1);
            l += __shfl_xor(l, 2);
            l += __shfl_xor(l, 4);
            l += __shfl_xor(l, 8);
            inv[r] = 1.0f / l;
        }
        #pragma unroll
        for (int dt = 0; dt < 4; dt++)
            #pragma unroll
            for (int r = 0; r < 4; r++) {
                const int q = q0 + m*16 + quad*4 + r;
                attn_out[(btok + q) * H + h*HDIM + dt*16 + l16] = f2bf(o[m][dt][r] * inv[r]);
            }
    }
}

// ---------------------------------------------------------------------------
extern "C" void kernel_launch(void* const* d_in, const int* in_sizes, int n_in,
                              void* d_out, int out_size, void* d_ws, size_t ws_size,
                              hipStream_t stream)
{
    const float* x   = (const float*)d_in[0];
    const int* mask  = (const int*)d_in[1];
    const float* Wq  = (const float*)d_in[2];
    const float* bq  = (const float*)d_in[3];
    const float* Aq  = (const float*)d_in[4];
    const float* Bq  = (const float*)d_in[5];
    const float* Wk  = (const float*)d_in[6];
    const float* bk  = (const float*)d_in[7];
    const float* Wv  = (const float*)d_in[8];
    const float* bv  = (const float*)d_in[9];
    const float* Av  = (const float*)d_in[10];
    const float* Bv  = (const float*)d_in[11];
    const float* Wo  = (const float*)d_in[12];
    const float* bo  = (const float*)d_in[13];

    char* ws = (char*)d_ws;
    u16*   xb      = (u16*)  (ws);                 // 12,582,912 B (reused as vt)
    u16*   Wall    = (u16*)  (ws + 12582912);      //  3,538,944 B
    u16*   Wobf    = (u16*)  (ws + 16121856);      //  1,179,648 B
    float* biasall = (float*)(ws + 17301504);      //      9,216 B
    u16*   qkv     = (u16*)  (ws + 17310720);      // 37,748,736 B
    u16*   attn_o  = (u16*)  (ws + 55059456);      // 12,582,912 B (end 67,642,368)
    u16*   vt      = xb;     // xb dead after QKV GEMM; reuse for V^T

    prep_kernel<<<PREP_BLOCKS + CVT_BLOCKS, 256, 0, stream>>>(
        Wq, bq, Aq, Bq, Wk, bk, Wv, bv, Av, Bv, Wo, x, Wall, Wobf, biasall, xb);
    gemm_bt<1,128,18><<<18 * (BT/128), 256, 0, stream>>>(xb, Wall, biasall, qkv, H, C3);
    vtrans_kernel<<<dim3(TSEQ/64, BATCH*NHEAD), 256, 0, stream>>>(qkv, vt);
    attn_kernel<<<dim3(TSEQ/128, BATCH*NHEAD), 256, 0, stream>>>(qkv, vt, mask, attn_o);
    gemm_bt<0,64,6><<<6 * (BT/64), 256, 0, stream>>>(attn_o, Wobf, bo, d_out, H, H);
}

// Round 10
// 201.480 us; speedup vs baseline: 1.1100x; 1.0568x over previous
//
#include <hip/hip_runtime.h>
#include <stdint.h>

#define H 768
#define NHEAD 12
#define HDIM 64
#define BATCH 16
#define TSEQ 512
#define BT (BATCH*TSEQ)      // 8192 tokens
#define C3 (3*H)             // 2304
#define LDQK 1536            // packed Q,K row stride

typedef __attribute__((ext_vector_type(8))) short short8;
typedef __attribute__((ext_vector_type(4))) float floatx4;
typedef unsigned short u16;

__device__ __forceinline__ u16 f2bf(float f) {
    union { float f; unsigned int u; } v; v.f = f;
    unsigned int u = v.u;
    return (u16)((u + 0x7FFFu + ((u >> 16) & 1u)) >> 16);
}

// async global->LDS, 16B per lane; LDS dest = wave-uniform base + lane*16
__device__ __forceinline__ void async_ld16(const void* g, void* l) {
    __builtin_amdgcn_global_load_lds((__attribute__((address_space(1))) void*)g,
                                     (__attribute__((address_space(3))) void*)l,
                                     16, 0, 0);
}

// ---------------------------------------------------------------------------
// Prep (merged): blocks [0,9216): Wall/Wobf/bias; blocks [9216,15360): x->bf16
// ---------------------------------------------------------------------------
#define PREP_BLOCKS 9216     // 4*H*H/256
#define CVT_BLOCKS  6144     // BT*H/1024
__global__ void prep_kernel(const float* __restrict__ Wq, const float* __restrict__ bq,
                            const float* __restrict__ Aq, const float* __restrict__ Bq,
                            const float* __restrict__ Wk, const float* __restrict__ bk,
                            const float* __restrict__ Wv, const float* __restrict__ bv,
                            const float* __restrict__ Av, const float* __restrict__ Bv,
                            const float* __restrict__ Wo, const float* __restrict__ x,
                            u16* __restrict__ Wall, u16* __restrict__ Wobf,
                            float* __restrict__ bias_all, u16* __restrict__ xb)
{
    const int bid = blockIdx.x;
    if (bid >= PREP_BLOCKS) {
        const int i = ((bid - PREP_BLOCKS) * 256 + threadIdx.x) * 4;
        const float4 v = *(const float4*)(x + i);
        u16 o[4] = { f2bf(v.x), f2bf(v.y), f2bf(v.z), f2bf(v.w) };
        *(uint2*)(xb + i) = *(const uint2*)o;
        return;
    }
    const int idx = bid * 256 + threadIdx.x;   // < 4*H*H
    const int r = idx / H;
    const int c = idx - r * H;
    if (r < H) {
        float v = Wq[idx] + 2.0f * (Bq[r*4+0]*Aq[c] + Bq[r*4+1]*Aq[H+c] +
                                    Bq[r*4+2]*Aq[2*H+c] + Bq[r*4+3]*Aq[3*H+c]);
        Wall[idx] = f2bf(v);
    } else if (r < 2*H) {
        Wall[idx] = f2bf(Wk[idx - H*H]);
    } else if (r < 3*H) {
        const int rr = r - 2*H;
        float v = Wv[rr*H + c] + 2.0f * (Bv[rr*4+0]*Av[c] + Bv[rr*4+1]*Av[H+c] +
                                         Bv[rr*4+2]*Av[2*H+c] + Bv[rr*4+3]*Av[3*H+c]);
        Wall[idx] = f2bf(v);
    } else {
        Wobf[idx - 3*H*H] = f2bf(Wo[idx - 3*H*H]);
    }
    if (idx < C3) {
        bias_all[idx] = (idx < H) ? bq[idx] : (idx < 2*H ? bk[idx - H] : bv[idx - 2*H]);
    }
}

// ---------------------------------------------------------------------------
// GEMM: C[M][N] = A[M][K] * B[N][K]^T + bias   (A,B bf16, acc fp32)
// r4 K-loop (BK=64, XOR-swizzled LDS, 0 conflicts) + plain epilogue + XCD
// block remap (r9: FETCH -56%).
// MAP 0: m-comb per XCD, n-major (A-panel L2-resident per XCD).
// MAP 1: n-comb per XCD, m fastest (B-panel L2-resident; for gemmV).
// MODE 0: fp32 C, per-n bias.  MODE 1: bf16 C, per-n bias.
// MODE 2: transposed-V output vt[bh][d][t] (m=d_global, n=token), per-m bias
//         — coalesced: lanes span consecutive t. Replaces the vtrans kernel.
// MB/NB: m-/n-block counts (grid.x = MB*NB).
// ---------------------------------------------------------------------------
template<int MODE, int TM, int NB, int MB, int MAP>
__global__ __launch_bounds__(256)
void gemm_bt(const u16* __restrict__ A, const u16* __restrict__ Bw,
             const float* __restrict__ bias, void* __restrict__ Cout,
             int K, int ldc)
{
    constexpr int MT = TM / 32;            // m-tiles per wave (4 or 2)
    __shared__ u16 Ablk[TM * 64];
    __shared__ u16 Bblk[128 * 64];
    const int tid  = threadIdx.x;
    const int wave = tid >> 6;
    const int lane = tid & 63;
    const int quad = lane >> 4;
    const int l16  = lane & 15;

    int m0, n0;
    {
        const int j   = blockIdx.x;
        const int xcd = j & 7;
        const int loc = j >> 3;
        if (MAP == 0) {
            constexpr int Mx = MB / 8;
            const int dm = loc % Mx;
            const int nb = loc / Mx;
            m0 = (xcd + 8*dm) * TM;
            n0 = nb * 128;
        } else {
            const int dm = loc % MB;
            const int nl = loc / MB;
            m0 = dm * TM;
            n0 = (xcd + 8*nl) * 128;
        }
    }

    const int mw = (wave & 1) * (TM / 2);
    const int nw = (wave >> 1) * 64;

    // staging: wave covers A rows [wave*(TM/4), +TM/4), B rows [wave*32,+32);
    // each async op = 8 rows. lane i -> row r8=i>>3, phys chunk i&7 holds
    // logical chunk (i&7)^r8 (XOR swizzle; conflict-free fragment reads)
    const int r8 = lane >> 3;
    const int kgs = ((lane & 7) ^ r8) * 8;
    const u16* gA = A  + (size_t)(m0 + wave*(TM/4) + r8) * K + kgs;
    const u16* gB = Bw + (size_t)(n0 + wave*32      + r8) * K + kgs;
    u16* lA = Ablk + wave * (TM/4) * 64;
    u16* lB = Bblk + wave * 32 * 64;

    floatx4 acc[MT][4] = {};
    const int sw = l16 & 7;    // reader swizzle key (row&7 == l16&7)

    for (int k0 = 0; k0 < K; k0 += 64) {
        __syncthreads();
        #pragma unroll
        for (int jj = 0; jj < TM/32; jj++)
            async_ld16(gA + k0 + (size_t)(jj*8) * K, lA + jj*8*64);
        #pragma unroll
        for (int jj = 0; jj < 4; jj++)
            async_ld16(gB + k0 + (size_t)(jj*8) * K, lB + jj*8*64);
        __syncthreads();
        #pragma unroll
        for (int kk = 0; kk < 2; kk++) {
            short8 af[MT], bfr[4];
            #pragma unroll
            for (int mt = 0; mt < MT; mt++)
                af[mt] = *(const short8*)(Ablk + (mw + mt*16 + l16)*64 + ((quad + 4*kk) ^ sw)*8);
            #pragma unroll
            for (int nt = 0; nt < 4; nt++)
                bfr[nt] = *(const short8*)(Bblk + (nw + nt*16 + l16)*64 + ((quad + 4*kk) ^ sw)*8);
            #pragma unroll
            for (int mt = 0; mt < MT; mt++)
                #pragma unroll
                for (int nt = 0; nt < 4; nt++)
                    acc[mt][nt] = __builtin_amdgcn_mfma_f32_16x16x32_bf16(af[mt], bfr[nt], acc[mt][nt], 0, 0, 0);
        }
    }

    // epilogue: C layout col=lane&15, row=quad*4+reg
    if (MODE == 2) {
        // vt[bh][d][t] <- C[m=d_global][n=token], per-m bias, coalesced in l16
        #pragma unroll
        for (int mt = 0; mt < MT; mt++) {
            #pragma unroll
            for (int r = 0; r < 4; r++) {
                const int m  = m0 + mw + mt*16 + quad*4 + r;
                const float bv = bias[m];
                const int hh = m >> 6, d = m & 63;
                #pragma unroll
                for (int nt = 0; nt < 4; nt++) {
                    const int n = n0 + nw + nt*16 + l16;
                    const int b = n >> 9, t = n & 511;
                    ((u16*)Cout)[((size_t)((b*NHEAD + hh)*HDIM + d))*TSEQ + t]
                        = f2bf(acc[mt][nt][r] + bv);
                }
            }
        }
    } else {
        #pragma unroll
        for (int nt = 0; nt < 4; nt++) {
            const int n = n0 + nw + nt*16 + l16;
            const float bv = bias[n];
            #pragma unroll
            for (int mt = 0; mt < MT; mt++) {
                #pragma unroll
                for (int r = 0; r < 4; r++) {
                    const int m = m0 + mw + mt*16 + quad*4 + r;
                    const float v = acc[mt][nt][r] + bv;
                    if (MODE == 1) ((u16*)Cout)[(size_t)m * ldc + n] = f2bf(v);
                    else           ((float*)Cout)[(size_t)m * ldc + n] = v;
                }
            }
        }
    }
}

// ---------------------------------------------------------------------------
// Attention: block-shared double-buffered LDS K/V staging, 1 barrier/iter,
// XOR-swizzled LDS. Q,K from qk[8192][1536]; V^T from vt[bh][d][t].
// Block = (b,h,128 q); wave owns 32 q rows.
// ---------------------------------------------------------------------------
#define PSTRIDE 40   // u16; 80 B rows: conflict-free writes + b128 reads

__global__ __launch_bounds__(256)
void attn_kernel(const u16* __restrict__ qk, const u16* __restrict__ vt,
                 const int* __restrict__ mask, u16* __restrict__ attn_out)
{
    __shared__ float maskadd[TSEQ];                 // 2 KB
    __shared__ u16 Kbuf[2][32 * 64];                // 8 KB  [key][d], swizzled
    __shared__ u16 Vbuf[2][64 * 32];                // 8 KB  [d][key], swizzled
    __shared__ u16 Pbuf[4][2][16 * PSTRIDE];        // 10 KB

    const int qt = blockIdx.x;        // 0..3 (128 q rows per block)
    const int bh = blockIdx.y;        // 0..191
    const int b = bh / NHEAD, h = bh - b * NHEAD;
    const int tid  = threadIdx.x;
    const int wave = tid >> 6;
    const int lane = tid & 63;
    const int quad = lane >> 4;
    const int l16  = lane & 15;

    for (int i = tid; i < TSEQ; i += 256)
        maskadd[i] = (mask[b*TSEQ + i] == 0) ? -1e9f : 0.0f;

    const size_t btok = (size_t)b * TSEQ;
    const int q0 = qt * 128 + wave * 32;

    // Q fragments for 2 row-tiles: A[m=l16][k=quad*8+j], two d-halves
    short8 qf[2][2];
    #pragma unroll
    for (int m = 0; m < 2; m++) {
        const u16* qp = qk + (btok + q0 + m*16 + l16) * LDQK + h*HDIM + quad*8;
        qf[m][0] = *(const short8*)qp;
        qf[m][1] = *(const short8*)(qp + 32);
    }

    const u16* kglob = qk + btok * LDQK + H + h*HDIM;   // K rows, stride LDQK
    const u16* vglob = vt + (size_t)bh * HDIM * TSEQ;   // V^T rows, stride TSEQ

    auto stage = [&](int kb, int pp) {
        {   // K[key][d]: lane i -> key kb+w*8+(i>>3), phys chunk i&7 = logical ^ (key&7)
            const int r = lane >> 3;
            const int g = (lane & 7) ^ r;
            async_ld16(kglob + (size_t)(kb + wave*8 + r) * LDQK + g*8,
                       &Kbuf[pp][wave*8*64]);
        }
        {   // V^T[d][key]: lane i -> d w*16+(i>>2), phys chunk i&3 = logical ^ ((d>>1)&3)
            const int dr = lane >> 2;
            const int g  = (lane & 3) ^ ((dr >> 1) & 3);
            async_ld16(vglob + (size_t)(wave*16 + dr) * TSEQ + kb + g*8,
                       &Vbuf[pp][wave*16*32]);
        }
    };

    floatx4 o[2][4] = {};              // 2 x (16q x 64d), C-layout
    float lsum[2][4] = {};

    auto compute = [&](int kb, int pp) {
        const u16* Kb_ = Kbuf[pp];
        const u16* Vb_ = Vbuf[pp];
        short8 kf[2][2];
        #pragma unroll
        for (int t = 0; t < 2; t++)
            #pragma unroll
            for (int h2 = 0; h2 < 2; h2++)
                kf[t][h2] = *(const short8*)(Kb_ + (t*16 + l16)*64 + (((h2*4 + quad) ^ (l16 & 7))*8));
        short8 vf[4];
        #pragma unroll
        for (int dt = 0; dt < 4; dt++)
            vf[dt] = *(const short8*)(Vb_ + (dt*16 + l16)*32 + ((quad ^ ((l16 >> 1) & 3))*8));

        floatx4 s[2][2];
        #pragma unroll
        for (int m = 0; m < 2; m++)
            #pragma unroll
            for (int t = 0; t < 2; t++) {
                floatx4 acc = {0.f, 0.f, 0.f, 0.f};
                acc = __builtin_amdgcn_mfma_f32_16x16x32_bf16(qf[m][0], kf[t][0], acc, 0, 0, 0);
                acc = __builtin_amdgcn_mfma_f32_16x16x32_bf16(qf[m][1], kf[t][1], acc, 0, 0, 0);
                s[m][t] = acc;
            }
        const float m0 = maskadd[kb + l16];
        const float m1 = maskadd[kb + 16 + l16];
        #pragma unroll
        for (int m = 0; m < 2; m++) {
            u16* Pw = Pbuf[wave][m];
            #pragma unroll
            for (int r = 0; r < 4; r++) {
                const float p0 = __expf(s[m][0][r] * 0.125f + m0);
                const float p1 = __expf(s[m][1][r] * 0.125f + m1);
                lsum[m][r] += p0 + p1;
                Pw[(quad*4 + r) * PSTRIDE + l16]      = f2bf(p0);
                Pw[(quad*4 + r) * PSTRIDE + 16 + l16] = f2bf(p1);
            }
        }
        #pragma unroll
        for (int m = 0; m < 2; m++) {
            const short8 pa = *(const short8*)(Pbuf[wave][m] + l16 * PSTRIDE + quad*8);
            #pragma unroll
            for (int dt = 0; dt < 4; dt++)
                o[m][dt] = __builtin_amdgcn_mfma_f32_16x16x32_bf16(pa, vf[dt], o[m][dt], 0, 0, 0);
        }
    };

    stage(0, 0);
    for (int it = 0; it < 16; it++) {
        __syncthreads();
        if (it < 15) stage((it + 1) * 32, (it + 1) & 1);
        compute(it * 32, it & 1);
    }

    #pragma unroll
    for (int m = 0; m < 2; m++) {
        float inv[4];
        #pragma unroll
        for (int r = 0; r < 4; r++) {
            float l = lsum[m][r];
            l += __shfl_xor(l, 1);
            l += __shfl_xor(l, 2);
            l += __shfl_xor(l, 4);
            l += __shfl_xor(l, 8);
            inv[r] = 1.0f / l;
        }
        #pragma unroll
        for (int dt = 0; dt < 4; dt++)
            #pragma unroll
            for (int r = 0; r < 4; r++) {
                const int q = q0 + m*16 + quad*4 + r;
                attn_out[(btok + q) * H + h*HDIM + dt*16 + l16] = f2bf(o[m][dt][r] * inv[r]);
            }
    }
}

// ---------------------------------------------------------------------------
extern "C" void kernel_launch(void* const* d_in, const int* in_sizes, int n_in,
                              void* d_out, int out_size, void* d_ws, size_t ws_size,
                              hipStream_t stream)
{
    const float* x   = (const float*)d_in[0];
    const int* mask  = (const int*)d_in[1];
    const float* Wq  = (const float*)d_in[2];
    const float* bq  = (const float*)d_in[3];
    const float* Aq  = (const float*)d_in[4];
    const float* Bq  = (const float*)d_in[5];
    const float* Wk  = (const float*)d_in[6];
    const float* bk  = (const float*)d_in[7];
    const float* Wv  = (const float*)d_in[8];
    const float* bv  = (const float*)d_in[9];
    const float* Av  = (const float*)d_in[10];
    const float* Bv  = (const float*)d_in[11];
    const float* Wo  = (const float*)d_in[12];
    const float* bo  = (const float*)d_in[13];

    char* ws = (char*)d_ws;
    u16*   xb      = (u16*)  (ws);                 // 12,582,912 B
    u16*   Wall    = (u16*)  (ws + 12582912);      //  3,538,944 B
    u16*   Wobf    = (u16*)  (ws + 16121856);      //  1,179,648 B
    float* biasall = (float*)(ws + 17301504);      //      9,216 B
    u16*   qk      = (u16*)  (ws + 17310720);      // 25,165,824 B
    u16*   vt      = (u16*)  (ws + 42476544);      // 12,582,912 B
    u16*   attn_o  = (u16*)  (ws + 55059456);      // 12,582,912 B (end 67,642,368)

    prep_kernel<<<PREP_BLOCKS + CVT_BLOCKS, 256, 0, stream>>>(
        Wq, bq, Aq, Bq, Wk, bk, Wv, bv, Av, Bv, Wo, x, Wall, Wobf, biasall, xb);
    // QK GEMM: M=8192(tokens, 64 blocks), N=1536 (12 n-blocks), MAP0
    gemm_bt<1,128,12,64,0><<<12*64, 256, 0, stream>>>(xb, Wall, biasall, qk, H, LDQK);
    // V GEMM (transposed out): M=768 (12 blocks of 64), N=8192 (64 n-blocks), MAP1
    gemm_bt<2,64,64,12,1><<<64*12, 256, 0, stream>>>(Wall + (size_t)2*H*H, xb,
                                                     biasall + 2*H, vt, H, 0);
    attn_kernel<<<dim3(TSEQ/128, BATCH*NHEAD), 256, 0, stream>>>(qk, vt, mask, attn_o);
    // Output GEMM: M=8192 (128 blocks of 64), N=768 (6 n-blocks), MAP0
    gemm_bt<0,64,6,128,0><<<6*128, 256, 0, stream>>>(attn_o, Wobf, bo, d_out, H, H);
}